// Round 12
// baseline (1407.769 us; speedup 1.0000x reference)
//
#include <hip/hip_runtime.h>
#include <hip/hip_fp16.h>
#include <stdint.h>
#include <cmath>

static constexpr int NUM_LEVELS = 16;
static constexpr uint32_t HASH_SIZE = 1u << 19;
static constexpr uint32_t HMASK = HASH_SIZE - 1u;
static constexpr int NB = 32;                     // bucket grid per axis
static constexpr int NBUCKETS = NB * NB * NB;     // 32768
static constexpr int CAP = 128;                   // padded slots/bucket (avg fill ~64)
static constexpr int OVCAP = 8192;                // overflow list capacity

typedef float    f2_t __attribute__((ext_vector_type(2)));
typedef float    f4_t __attribute__((ext_vector_type(4)));
typedef uint32_t u4_t __attribute__((ext_vector_type(4)));

struct ResArr { float r[NUM_LEVELS]; };

// ---------- corner indices + trilinear weights for one level (order = _OFFSETS)
__device__ __forceinline__ void make_corners(
    float px, float py, float pz, float res, uint32_t* idx, float* w)
{
    float sx = ((px + 1.0f) * 0.5f) * res;
    float sy = ((py + 1.0f) * 0.5f) * res;
    float sz = ((pz + 1.0f) * 0.5f) * res;

    float fx = floorf(sx), fy = floorf(sy), fz = floorf(sz);
    float rx = sx - fx, ry = sy - fy, rz = sz - fz;

    float x0f = fminf(fmaxf(fx, 0.f), res), x1f = fminf(fmaxf(fx + 1.f, 0.f), res);
    float y0f = fminf(fmaxf(fy, 0.f), res), y1f = fminf(fmaxf(fy + 1.f, 0.f), res);
    float z0f = fminf(fmaxf(fz, 0.f), res), z1f = fminf(fmaxf(fz + 1.f, 0.f), res);

    uint32_t x0 = (uint32_t)x0f, x1 = (uint32_t)x1f;
    uint32_t hy0 = (uint32_t)y0f * 2654435761u, hy1 = (uint32_t)y1f * 2654435761u;
    uint32_t hz0 = (uint32_t)z0f * 805459861u,  hz1 = (uint32_t)z1f * 805459861u;

    float wx0 = 1.f - rx, wx1 = rx;
    float wy0 = 1.f - ry, wy1 = ry;
    float wz0 = 1.f - rz, wz1 = rz;

    idx[0] = (x0 ^ hy0 ^ hz0) & HMASK; w[0] = (wx0 * wy0) * wz0;
    idx[1] = (x0 ^ hy0 ^ hz1) & HMASK; w[1] = (wx0 * wy0) * wz1;
    idx[2] = (x0 ^ hy1 ^ hz0) & HMASK; w[2] = (wx0 * wy1) * wz0;
    idx[3] = (x0 ^ hy1 ^ hz1) & HMASK; w[3] = (wx0 * wy1) * wz1;
    idx[4] = (x1 ^ hy0 ^ hz0) & HMASK; w[4] = (wx1 * wy0) * wz0;
    idx[5] = (x1 ^ hy0 ^ hz1) & HMASK; w[5] = (wx1 * wy0) * wz1;
    idx[6] = (x1 ^ hy1 ^ hz0) & HMASK; w[6] = (wx1 * wy1) * wz0;
    idx[7] = (x1 ^ hy1 ^ hz1) & HMASK; w[7] = (wx1 * wy1) * wz1;
}

// ---------- all 16 levels for one point from packed fp16 tables.
// Coarse/mid pairs (p<3): cached gathers (real L1 reuse after spatial sort).
// Fine pairs (p>=3): NON-TEMPORAL gathers -- no L1 allocation: saves the
// fill-tag cycles and stops fine-level streams evicting the mid-level lines.
__device__ __forceinline__ void enc_all16(
    float px, float py, float pz, const uint32_t* __restrict__ tbl16,
    const ResArr& ra, f4_t r[8])
{
    #pragma unroll
    for (int p = 0; p < 8; ++p) {
        const uint32_t* tA = tbl16 + (size_t)(2 * p)     * HASH_SIZE;
        const uint32_t* tB = tbl16 + (size_t)(2 * p + 1) * HASH_SIZE;
        uint32_t idxA[8], idxB[8];
        float wA[8], wB[8];
        make_corners(px, py, pz, ra.r[2 * p],     idxA, wA);
        make_corners(px, py, pz, ra.r[2 * p + 1], idxB, wB);

        uint32_t g[16];
        if (p < 3) {
            #pragma unroll
            for (int i = 0; i < 8; ++i) g[i]     = tA[idxA[i]];
            #pragma unroll
            for (int i = 0; i < 8; ++i) g[8 + i] = tB[idxB[i]];
        } else {
            #pragma unroll
            for (int i = 0; i < 8; ++i) g[i]     = __builtin_nontemporal_load(tA + idxA[i]);
            #pragma unroll
            for (int i = 0; i < 8; ++i) g[8 + i] = __builtin_nontemporal_load(tB + idxB[i]);
        }

        float a0 = 0.f, a1 = 0.f, b0 = 0.f, b1 = 0.f;
        #pragma unroll
        for (int i = 0; i < 8; ++i) {
            union { uint32_t u; __half2 h2; } c; c.u = g[i];
            float2 f = __half22float2(c.h2);
            a0 += wA[i] * f.x; a1 += wA[i] * f.y;
        }
        #pragma unroll
        for (int i = 0; i < 8; ++i) {
            union { uint32_t u; __half2 h2; } c; c.u = g[8 + i];
            float2 f = __half22float2(c.h2);
            b0 += wB[i] * f.x; b1 += wB[i] * f.y;
        }
        r[p] = (f4_t){a0, a1, b0, b1};
    }
}

// ---------- conv: 8 table entries (64B in / 32B out) per thread
__global__ __launch_bounds__(256) void convert_kernel8(
    const f4_t* __restrict__ tables4, uint32_t* __restrict__ tbl16, int nthreads)
{
    int t = blockIdx.x * 256 + threadIdx.x;
    if (t >= nthreads) return;
    const f4_t* src = tables4 + (size_t)t * 4;
    f4_t v0 = __builtin_nontemporal_load(src + 0);
    f4_t v1 = __builtin_nontemporal_load(src + 1);
    f4_t v2 = __builtin_nontemporal_load(src + 2);
    f4_t v3 = __builtin_nontemporal_load(src + 3);
    union { __half2 h2; uint32_t u; } c0, c1, c2, c3, c4, c5, c6, c7;
    c0.h2 = __floats2half2_rn(v0.x, v0.y); c1.h2 = __floats2half2_rn(v0.z, v0.w);
    c2.h2 = __floats2half2_rn(v1.x, v1.y); c3.h2 = __floats2half2_rn(v1.z, v1.w);
    c4.h2 = __floats2half2_rn(v2.x, v2.y); c5.h2 = __floats2half2_rn(v2.z, v2.w);
    c6.h2 = __floats2half2_rn(v3.x, v3.y); c7.h2 = __floats2half2_rn(v3.z, v3.w);
    u4_t o0 = {c0.u, c1.u, c2.u, c3.u};
    u4_t o1 = {c4.u, c5.u, c6.u, c7.u};
    u4_t* dst = reinterpret_cast<u4_t*>(tbl16) + (size_t)t * 2;
    __builtin_nontemporal_store(o0, dst + 0);
    __builtin_nontemporal_store(o1, dst + 1);
}

// ---------- scatter: 4 points per thread via 3 coalesced f4 loads
__global__ __launch_bounds__(256) void scatter4_kernel(
    const f4_t* __restrict__ pos4, f4_t* __restrict__ padded,
    uint32_t* __restrict__ counts, uint32_t* __restrict__ ovcnt,
    f4_t* __restrict__ ovlist, int nquads)
{
    int q = blockIdx.x * 256 + threadIdx.x;
    if (q >= nquads) return;
    f4_t a = __builtin_nontemporal_load(pos4 + (size_t)q * 3 + 0);
    f4_t b = __builtin_nontemporal_load(pos4 + (size_t)q * 3 + 1);
    f4_t c = __builtin_nontemporal_load(pos4 + (size_t)q * 3 + 2);
    float xs[4] = {a.x, a.w, b.z, c.y};
    float ys[4] = {a.y, b.x, b.w, c.z};
    float zs[4] = {a.z, b.y, c.x, c.w};
    #pragma unroll
    for (int j = 0; j < 4; ++j) {
        int kx = min(max((int)((xs[j] + 1.f) * 16.f), 0), NB - 1);
        int ky = min(max((int)((ys[j] + 1.f) * 16.f), 0), NB - 1);
        int kz = min(max((int)((zs[j] + 1.f) * 16.f), 0), NB - 1);
        int bucket = (kx << 10) | (ky << 5) | kz;
        uint32_t rank = atomicAdd(&counts[bucket], 1u);
        f4_t rec = {xs[j], ys[j], zs[j], __uint_as_float((uint32_t)(q * 4 + j))};
        if (rank < (uint32_t)CAP) {
            padded[(size_t)bucket * CAP + rank] = rec;
        } else {
            uint32_t ov = atomicAdd(ovcnt, 1u);   // ~never (Poisson(64) > 128)
            if (ov < (uint32_t)OVCAP) ovlist[ov] = rec;
        }
    }
}

// ---------- main: one thread = one padded slot (gid == bucket*CAP + slot).
// Chunked XCD swizzle keeps each spatial region on one XCD's L2.
__global__ __launch_bounds__(256) void hashenc_padded_kernel(
    const f4_t* __restrict__ padded, const uint32_t* __restrict__ counts,
    const uint32_t* __restrict__ tbl16, float* __restrict__ out,
    int nchunk, ResArr ra)
{
    int bid = blockIdx.x;
    int sbid = (bid & 7) * nchunk + (bid >> 3);
    int gid = sbid * 256 + threadIdx.x;
    int bucket = gid >> 7;                 // CAP == 128
    int slot   = gid & (CAP - 1);
    uint32_t cnt = counts[bucket];
    if (slot >= (int)min(cnt, (uint32_t)CAP)) return;

    f4_t t = padded[gid];
    float px = t.x, py = t.y, pz = t.z;
    uint32_t orig = __float_as_uint(t.w);

    f4_t r[8];
    enc_all16(px, py, pz, tbl16, ra, r);

    // cached stores: full 128B row -> clean line write-back, no RMW
    f4_t* dst = reinterpret_cast<f4_t*>(out + (size_t)orig * 32);
    #pragma unroll
    for (int k = 0; k < 8; ++k) dst[k] = r[k];
}

// ---------- overflow cleanup (empty in practice; guarantees correctness)
__global__ __launch_bounds__(256) void overflow_kernel(
    const f4_t* __restrict__ ovlist, const uint32_t* __restrict__ ovcnt,
    const uint32_t* __restrict__ tbl16, float* __restrict__ out, ResArr ra)
{
    uint32_t n = min(*ovcnt, (uint32_t)OVCAP);
    for (uint32_t i = threadIdx.x; i < n; i += 256) {
        f4_t t = ovlist[i];
        f4_t r[8];
        enc_all16(t.x, t.y, t.z, tbl16, ra, r);
        f4_t* dst = reinterpret_cast<f4_t*>(out + (size_t)__float_as_uint(t.w) * 32);
        #pragma unroll
        for (int k = 0; k < 8; ++k) dst[k] = r[k];
    }
}

// ================= fallback paths =================
__global__ __launch_bounds__(256) void convert_kernel(
    const f2_t* __restrict__ tables, uint32_t* __restrict__ out, int total)
{
    int i = blockIdx.x * 256 + threadIdx.x;
    if (i >= total) return;
    f2_t v = __builtin_nontemporal_load(&tables[i]);
    __half2 h = __floats2half2_rn(v.x, v.y);
    union { __half2 h2; uint32_t u; } cvt; cvt.h2 = h;
    __builtin_nontemporal_store(cvt.u, &out[i]);
}

__global__ __launch_bounds__(256) void hist_kernel(
    const float* __restrict__ pos, uint32_t* __restrict__ counts, int n)
{
    int i = blockIdx.x * 256 + threadIdx.x;
    if (i >= n) return;
    int kx = min(max((int)((pos[(size_t)i*3+0] + 1.f) * 16.f), 0), NB - 1);
    int ky = min(max((int)((pos[(size_t)i*3+1] + 1.f) * 16.f), 0), NB - 1);
    int kz = min(max((int)((pos[(size_t)i*3+2] + 1.f) * 16.f), 0), NB - 1);
    atomicAdd(&counts[(kx << 10) | (ky << 5) | kz], 1u);
}

__global__ __launch_bounds__(1024) void scan_kernel(
    const uint32_t* __restrict__ counts, uint32_t* __restrict__ offsets)
{
    __shared__ uint32_t lds[1024];
    int tid = threadIdx.x;
    uint32_t running = 0;
    for (int chunk = 0; chunk < NBUCKETS; chunk += 1024) {
        uint32_t v = counts[chunk + tid];
        lds[tid] = v;
        __syncthreads();
        #pragma unroll
        for (int off = 1; off < 1024; off <<= 1) {
            uint32_t t = (tid >= off) ? lds[tid - off] : 0u;
            __syncthreads();
            lds[tid] += t;
            __syncthreads();
        }
        offsets[chunk + tid] = running + lds[tid] - v;
        running += lds[1023];
        __syncthreads();
    }
}

__global__ __launch_bounds__(256) void scatter_kernel(
    const float* __restrict__ pos, uint32_t* __restrict__ offs,
    float4* __restrict__ sorted, int n)
{
    int i = blockIdx.x * 256 + threadIdx.x;
    if (i >= n) return;
    float px = pos[(size_t)i*3+0], py = pos[(size_t)i*3+1], pz = pos[(size_t)i*3+2];
    int kx = min(max((int)((px + 1.f) * 16.f), 0), NB - 1);
    int ky = min(max((int)((py + 1.f) * 16.f), 0), NB - 1);
    int kz = min(max((int)((pz + 1.f) * 16.f), 0), NB - 1);
    uint32_t slot = atomicAdd(&offs[(kx << 10) | (ky << 5) | kz], 1u);
    sorted[slot] = make_float4(px, py, pz, __uint_as_float((uint32_t)i));
}

__global__ __launch_bounds__(256) void hashenc_sorted_kernel(
    const float4* __restrict__ sorted, const uint32_t* __restrict__ tbl16,
    float* __restrict__ out, int n_points, int nchunk, ResArr ra)
{
    int bid = blockIdx.x;
    int sbid = (bid & 7) * nchunk + (bid >> 3);
    int gid = sbid * 256 + threadIdx.x;
    if (gid >= n_points) return;
    f4_t t = __builtin_nontemporal_load(reinterpret_cast<const f4_t*>(sorted) + gid);
    f4_t r[8];
    enc_all16(t.x, t.y, t.z, tbl16, ra, r);
    f4_t* dst = reinterpret_cast<f4_t*>(out + (size_t)__float_as_uint(t.w) * 32);
    #pragma unroll
    for (int k = 0; k < 8; ++k) dst[k] = r[k];
}

__global__ __launch_bounds__(256) void hashenc_fp32_kernel(
    const float* __restrict__ pos, const float* __restrict__ tables,
    float* __restrict__ out, int n_points, ResArr res_arr)
{
    int tid = blockIdx.x * 256 + threadIdx.x;
    if (tid >= n_points * NUM_LEVELS) return;
    int level = tid & (NUM_LEVELS - 1);
    int point = tid >> 4;
    float px = pos[(size_t)point*3+0], py = pos[(size_t)point*3+1], pz = pos[(size_t)point*3+2];
    uint32_t idx[8]; float w[8];
    make_corners(px, py, pz, res_arr.r[level], idx, w);
    const float2* tbl = reinterpret_cast<const float2*>(tables) + (size_t)level * HASH_SIZE;
    float acc0 = 0.f, acc1 = 0.f;
    #pragma unroll
    for (int i = 0; i < 8; ++i) {
        float2 f = tbl[idx[i]];
        acc0 += w[i] * f.x; acc1 += w[i] * f.y;
    }
    union { float acc[2]; double d; } u;
    u.acc[0] = acc0; u.acc[1] = acc1;
    __builtin_nontemporal_store(u.d, reinterpret_cast<double*>(out) + ((size_t)point * 16 + level));
}

extern "C" void kernel_launch(void* const* d_in, const int* in_sizes, int n_in,
                              void* d_out, int out_size, void* d_ws, size_t ws_size,
                              hipStream_t stream) {
    const float* pos    = (const float*)d_in[0];
    const float* tables = (const float*)d_in[1];
    float* out = (float*)d_out;
    int n_points = in_sizes[0] / 3;

    // Replicate numpy exactly: RESOLUTIONS[i] = int(floor(16 * exp((i*log(32))/15)))
    ResArr ra;
    const double log32 = log(32.0);
    for (int i = 0; i < NUM_LEVELS; ++i)
        ra.r[i] = (float)(int)floor(16.0 * exp(((double)i * log32) / 15.0));

    const size_t tbl_bytes = (size_t)NUM_LEVELS * HASH_SIZE * sizeof(uint32_t);   // 32 MiB
    const size_t pad_bytes = (size_t)NBUCKETS * CAP * sizeof(f4_t);               // 64 MiB
    const size_t cnt_bytes = (size_t)NBUCKETS * sizeof(uint32_t);                 // 128 KiB
    const size_t ov_bytes  = 16 + (size_t)OVCAP * sizeof(f4_t);
    const size_t need_pad  = tbl_bytes + pad_bytes + cnt_bytes + ov_bytes;        // ~96.3 MiB

    const size_t sorted_bytes = (size_t)n_points * sizeof(float4);
    const size_t need_sorted  = tbl_bytes + sorted_bytes + 2 * cnt_bytes;

    int pblocks = (n_points + 255) / 256;
    int ttotal  = NUM_LEVELS * (int)HASH_SIZE;

    if (ws_size >= need_pad && n_points <= (1 << 21) && (n_points & 3) == 0) {
        char* ws = (char*)d_ws;
        uint32_t* tbl16  = (uint32_t*)(ws);
        f4_t*     padded = (f4_t*)(ws + tbl_bytes);
        uint32_t* counts = (uint32_t*)(ws + tbl_bytes + pad_bytes);
        uint32_t* ovcnt  = (uint32_t*)(ws + tbl_bytes + pad_bytes + cnt_bytes);
        f4_t*     ovlist = (f4_t*)(ws + tbl_bytes + pad_bytes + cnt_bytes + 16);

        hipMemsetAsync(counts, 0, cnt_bytes + 16, stream);
        int cthreads = ttotal / 8;                            // 8 entries/thread
        convert_kernel8<<<(cthreads + 255) / 256, 256, 0, stream>>>(
            (const f4_t*)tables, tbl16, cthreads);
        int nquads = n_points / 4;
        scatter4_kernel<<<(nquads + 255) / 256, 256, 0, stream>>>(
            (const f4_t*)pos, padded, counts, ovcnt, ovlist, nquads);

        int nblocks = NBUCKETS * CAP / 256;                   // 16384
        int nchunk  = nblocks / 8;
        hashenc_padded_kernel<<<nblocks, 256, 0, stream>>>(
            padded, counts, tbl16, out, nchunk, ra);
        overflow_kernel<<<1, 256, 0, stream>>>(ovlist, ovcnt, tbl16, out, ra);
    } else if (ws_size >= need_sorted) {
        char* ws = (char*)d_ws;
        uint32_t* tbl16   = (uint32_t*)(ws);
        float4*   sorted  = (float4*)(ws + tbl_bytes);
        uint32_t* offsets = (uint32_t*)(ws + tbl_bytes + sorted_bytes);
        uint32_t* counts  = (uint32_t*)(ws + tbl_bytes + sorted_bytes + cnt_bytes);

        convert_kernel<<<(ttotal + 255) / 256, 256, 0, stream>>>(
            (const f2_t*)tables, tbl16, ttotal);
        hipMemsetAsync(counts, 0, cnt_bytes, stream);
        hist_kernel<<<pblocks, 256, 0, stream>>>(pos, counts, n_points);
        scan_kernel<<<1, 1024, 0, stream>>>(counts, offsets);
        scatter_kernel<<<pblocks, 256, 0, stream>>>(pos, offsets, sorted, n_points);
        int nchunk = (pblocks + 7) / 8;
        hashenc_sorted_kernel<<<nchunk * 8, 256, 0, stream>>>(
            sorted, tbl16, out, n_points, nchunk, ra);
    } else {
        long long total = (long long)n_points * NUM_LEVELS;
        hashenc_fp32_kernel<<<(int)((total + 255) / 256), 256, 0, stream>>>(
            pos, tables, out, n_points, ra);
    }
}

// Round 13
// 678.003 us; speedup vs baseline: 2.0763x; 2.0763x over previous
//
#include <hip/hip_runtime.h>
#include <hip/hip_fp16.h>
#include <stdint.h>
#include <cmath>

static constexpr int NUM_LEVELS = 16;
static constexpr uint32_t HASH_SIZE = 1u << 19;
static constexpr uint32_t HMASK = HASH_SIZE - 1u;
static constexpr int NB = 32;                     // bucket grid per axis
static constexpr int NBUCKETS = NB * NB * NB;     // 32768
static constexpr int CAP = 128;                   // padded slots/bucket (avg fill ~64)
static constexpr int OVCAP = 8192;                // overflow list capacity

// staged levels 0..9 (R=16..128): per-bucket LDS window W = ceil(R/32)+3
static constexpr int NSTAGED = 10;
__device__ __constant__ const int SW[NSTAGED]   = {4,4,4,4,5,5,5,6,7,7};
__device__ __constant__ const int SOFF[NSTAGED] = {0,64,128,192,256,381,506,631,847,1190};
static constexpr int STOT = 1533;                 // sum of W^3

typedef float    f2_t __attribute__((ext_vector_type(2)));
typedef float    f4_t __attribute__((ext_vector_type(4)));
typedef uint32_t u4_t __attribute__((ext_vector_type(4)));

struct ResArr { float r[NUM_LEVELS]; };

// ---------- per-axis clipped corner coords + weights (order matches _OFFSETS)
__device__ __forceinline__ void corner_setup(
    float px, float py, float pz, float res,
    int xi[2], int yi[2], int zi[2], float wx[2], float wy[2], float wz[2])
{
    float sx = ((px + 1.0f) * 0.5f) * res;
    float sy = ((py + 1.0f) * 0.5f) * res;
    float sz = ((pz + 1.0f) * 0.5f) * res;
    float fx = floorf(sx), fy = floorf(sy), fz = floorf(sz);
    float rx = sx - fx, ry = sy - fy, rz = sz - fz;
    xi[0] = (int)fminf(fmaxf(fx, 0.f), res);       xi[1] = (int)fminf(fmaxf(fx + 1.f, 0.f), res);
    yi[0] = (int)fminf(fmaxf(fy, 0.f), res);       yi[1] = (int)fminf(fmaxf(fy + 1.f, 0.f), res);
    zi[0] = (int)fminf(fmaxf(fz, 0.f), res);       zi[1] = (int)fminf(fmaxf(fz + 1.f, 0.f), res);
    wx[0] = 1.f - rx; wx[1] = rx;
    wy[0] = 1.f - ry; wy[1] = ry;
    wz[0] = 1.f - rz; wz[1] = rz;
}

// ---------- one level via global hash gather (cached; NO nontemporal -- r12 lesson)
__device__ __forceinline__ void enc_level_global(
    float px, float py, float pz, float res, const uint32_t* __restrict__ tbl,
    float& o0, float& o1)
{
    int xi[2], yi[2], zi[2]; float wx[2], wy[2], wz[2];
    corner_setup(px, py, pz, res, xi, yi, zi, wx, wy, wz);
    uint32_t hy0 = (uint32_t)yi[0] * 2654435761u, hy1 = (uint32_t)yi[1] * 2654435761u;
    uint32_t hz0 = (uint32_t)zi[0] * 805459861u,  hz1 = (uint32_t)zi[1] * 805459861u;
    uint32_t g[8];
    g[0] = tbl[((uint32_t)xi[0] ^ hy0 ^ hz0) & HMASK];
    g[1] = tbl[((uint32_t)xi[0] ^ hy0 ^ hz1) & HMASK];
    g[2] = tbl[((uint32_t)xi[0] ^ hy1 ^ hz0) & HMASK];
    g[3] = tbl[((uint32_t)xi[0] ^ hy1 ^ hz1) & HMASK];
    g[4] = tbl[((uint32_t)xi[1] ^ hy0 ^ hz0) & HMASK];
    g[5] = tbl[((uint32_t)xi[1] ^ hy0 ^ hz1) & HMASK];
    g[6] = tbl[((uint32_t)xi[1] ^ hy1 ^ hz0) & HMASK];
    g[7] = tbl[((uint32_t)xi[1] ^ hy1 ^ hz1) & HMASK];
    float a0 = 0.f, a1 = 0.f;
    #pragma unroll
    for (int c = 0; c < 8; ++c) {
        union { uint32_t u; __half2 h2; } cv; cv.u = g[c];
        float2 f = __half22float2(cv.h2);
        float w = (wx[c >> 2] * wy[(c >> 1) & 1]) * wz[c & 1];
        a0 += w * f.x; a1 += w * f.y;
    }
    o0 = a0; o1 = a1;
}

// ---------- all 16 levels via global hash (for overflow + fallback paths)
__device__ __forceinline__ void enc_all16(
    float px, float py, float pz, const uint32_t* __restrict__ tbl16,
    const ResArr& ra, f4_t r[8])
{
    #pragma unroll
    for (int p = 0; p < 8; ++p) {
        float a0, a1, b0, b1;
        enc_level_global(px, py, pz, ra.r[2*p],   tbl16 + (size_t)(2*p)   * HASH_SIZE, a0, a1);
        enc_level_global(px, py, pz, ra.r[2*p+1], tbl16 + (size_t)(2*p+1) * HASH_SIZE, b0, b1);
        r[p] = (f4_t){a0, a1, b0, b1};
    }
}

// ---------- conv: 8 table entries (64B in / 32B out) per thread
__global__ __launch_bounds__(256) void convert_kernel8(
    const f4_t* __restrict__ tables4, uint32_t* __restrict__ tbl16, int nthreads)
{
    int t = blockIdx.x * 256 + threadIdx.x;
    if (t >= nthreads) return;
    const f4_t* src = tables4 + (size_t)t * 4;
    f4_t v0 = __builtin_nontemporal_load(src + 0);
    f4_t v1 = __builtin_nontemporal_load(src + 1);
    f4_t v2 = __builtin_nontemporal_load(src + 2);
    f4_t v3 = __builtin_nontemporal_load(src + 3);
    union { __half2 h2; uint32_t u; } c0, c1, c2, c3, c4, c5, c6, c7;
    c0.h2 = __floats2half2_rn(v0.x, v0.y); c1.h2 = __floats2half2_rn(v0.z, v0.w);
    c2.h2 = __floats2half2_rn(v1.x, v1.y); c3.h2 = __floats2half2_rn(v1.z, v1.w);
    c4.h2 = __floats2half2_rn(v2.x, v2.y); c5.h2 = __floats2half2_rn(v2.z, v2.w);
    c6.h2 = __floats2half2_rn(v3.x, v3.y); c7.h2 = __floats2half2_rn(v3.z, v3.w);
    u4_t o0 = {c0.u, c1.u, c2.u, c3.u};
    u4_t o1 = {c4.u, c5.u, c6.u, c7.u};
    u4_t* dst = reinterpret_cast<u4_t*>(tbl16) + (size_t)t * 2;
    __builtin_nontemporal_store(o0, dst + 0);
    __builtin_nontemporal_store(o1, dst + 1);
}

// ---------- scatter: 4 points per thread via 3 coalesced f4 loads
__global__ __launch_bounds__(256) void scatter4_kernel(
    const f4_t* __restrict__ pos4, f4_t* __restrict__ padded,
    uint32_t* __restrict__ counts, uint32_t* __restrict__ ovcnt,
    f4_t* __restrict__ ovlist, int nquads)
{
    int q = blockIdx.x * 256 + threadIdx.x;
    if (q >= nquads) return;
    f4_t a = __builtin_nontemporal_load(pos4 + (size_t)q * 3 + 0);
    f4_t b = __builtin_nontemporal_load(pos4 + (size_t)q * 3 + 1);
    f4_t c = __builtin_nontemporal_load(pos4 + (size_t)q * 3 + 2);
    float xs[4] = {a.x, a.w, b.z, c.y};
    float ys[4] = {a.y, b.x, b.w, c.z};
    float zs[4] = {a.z, b.y, c.x, c.w};
    #pragma unroll
    for (int j = 0; j < 4; ++j) {
        int kx = min(max((int)((xs[j] + 1.f) * 16.f), 0), NB - 1);
        int ky = min(max((int)((ys[j] + 1.f) * 16.f), 0), NB - 1);
        int kz = min(max((int)((zs[j] + 1.f) * 16.f), 0), NB - 1);
        int bucket = (kx << 10) | (ky << 5) | kz;
        uint32_t rank = atomicAdd(&counts[bucket], 1u);
        f4_t rec = {xs[j], ys[j], zs[j], __uint_as_float((uint32_t)(q * 4 + j))};
        if (rank < (uint32_t)CAP) {
            padded[(size_t)bucket * CAP + rank] = rec;
        } else {
            uint32_t ov = atomicAdd(ovcnt, 1u);   // ~never (Poisson(64) > 128)
            if (ov < (uint32_t)OVCAP) ovlist[ov] = rec;
        }
    }
}

// ---------- main: block = 2 buckets. Stage levels 0..9's corner windows in LDS
// (no hashing on the hot path for them), direct hash-gather for levels 10..15.
// Chunked XCD swizzle keeps each spatial region on one XCD's L2.
__global__ __launch_bounds__(256) void hashenc_lds_kernel(
    const f4_t* __restrict__ padded, const uint32_t* __restrict__ counts,
    const uint32_t* __restrict__ tbl16, float* __restrict__ out,
    int nchunk, ResArr ra)
{
    __shared__ uint32_t slds[2][STOT];

    int bid = blockIdx.x;
    int sbid = (bid & 7) * nchunk + (bid >> 3);
    int tid = threadIdx.x;
    int bkt0 = sbid << 1;

    // ---- stage: 2*1533 entries, 256 threads -> 12 iters
    for (int e = tid; e < 2 * STOT; e += 256) {
        int lb  = (e >= STOT) ? 1 : 0;
        int idx = e - lb * STOT;
        int bucket = bkt0 + lb;
        int kx = bucket >> 10, ky = (bucket >> 5) & 31, kz = bucket & 31;
        int lvl, lx, ly, lz, W;
        if (idx < 256)      { lvl = idx >> 6; int loc = idx & 63;  W = 4; lz = loc & 3; ly = (loc >> 2) & 3; lx = loc >> 4; }
        else if (idx < 631) { int t = idx - 256; lvl = 4 + t / 125; int loc = t - (lvl - 4) * 125; W = 5; lz = loc % 5; int t2 = loc / 5; ly = t2 % 5; lx = t2 / 5; }
        else if (idx < 847) { lvl = 7; int loc = idx - 631; W = 6; lz = loc % 6; int t2 = loc / 6; ly = t2 % 6; lx = t2 / 6; }
        else                { int t = idx - 847; lvl = 8 + t / 343; int loc = t - (lvl - 8) * 343; W = 7; lz = loc % 7; int t2 = loc / 7; ly = t2 % 7; lx = t2 / 7; }
        float R = ra.r[lvl];
        int bx = (int)floorf((float)kx * R * 0.03125f) - 1;
        int by = (int)floorf((float)ky * R * 0.03125f) - 1;
        int bz = (int)floorf((float)kz * R * 0.03125f) - 1;
        uint32_t gx = (uint32_t)(bx + lx), gy = (uint32_t)(by + ly), gz = (uint32_t)(bz + lz);
        uint32_t h = gx ^ (gy * 2654435761u) ^ (gz * 805459861u);
        slds[lb][idx] = tbl16[(size_t)lvl * HASH_SIZE + (h & HMASK)];
    }
    __syncthreads();

    int gid = sbid * 256 + tid;
    int bucket = gid >> 7;                 // CAP == 128
    int slot   = gid & (CAP - 1);
    int lb     = tid >> 7;
    uint32_t cnt = counts[bucket];
    if (slot >= (int)min(cnt, (uint32_t)CAP)) return;

    f4_t t = padded[gid];
    float px = t.x, py = t.y, pz = t.z;
    uint32_t orig = __float_as_uint(t.w);
    int kx = bucket >> 10, ky = (bucket >> 5) & 31, kz = bucket & 31;
    const uint32_t* sb = slds[lb];

    f4_t r[8];
    // pairs 0..4: both levels staged in LDS
    #pragma unroll
    for (int p = 0; p < 5; ++p) {
        float acc[4];
        #pragma unroll
        for (int h2 = 0; h2 < 2; ++h2) {
            const int lvl = 2 * p + h2;
            const int W   = SW[lvl];
            const int off = SOFF[lvl];
            float R = ra.r[lvl];
            int bx = (int)floorf((float)kx * R * 0.03125f) - 1;
            int by = (int)floorf((float)ky * R * 0.03125f) - 1;
            int bz = (int)floorf((float)kz * R * 0.03125f) - 1;
            int xi[2], yi[2], zi[2]; float wx[2], wy[2], wz[2];
            corner_setup(px, py, pz, R, xi, yi, zi, wx, wy, wz);
            int lx0 = xi[0] - bx, lx1 = xi[1] - bx;
            int ly0 = yi[0] - by, ly1 = yi[1] - by;
            int lz0 = zi[0] - bz, lz1 = zi[1] - bz;
            float a0 = 0.f, a1 = 0.f;
            #pragma unroll
            for (int c = 0; c < 8; ++c) {
                int lx = (c & 4) ? lx1 : lx0;
                int ly = (c & 2) ? ly1 : ly0;
                int lz = (c & 1) ? lz1 : lz0;
                union { uint32_t u; __half2 hh; } cv;
                cv.u = sb[off + (lx * W + ly) * W + lz];
                float2 f = __half22float2(cv.hh);
                float w = (wx[c >> 2] * wy[(c >> 1) & 1]) * wz[c & 1];
                a0 += w * f.x; a1 += w * f.y;
            }
            acc[2 * h2] = a0; acc[2 * h2 + 1] = a1;
        }
        r[p] = (f4_t){acc[0], acc[1], acc[2], acc[3]};
    }
    // pairs 5..7: direct global hash gathers (cached)
    #pragma unroll
    for (int p = 5; p < 8; ++p) {
        float a0, a1, b0, b1;
        enc_level_global(px, py, pz, ra.r[2*p],   tbl16 + (size_t)(2*p)   * HASH_SIZE, a0, a1);
        enc_level_global(px, py, pz, ra.r[2*p+1], tbl16 + (size_t)(2*p+1) * HASH_SIZE, b0, b1);
        r[p] = (f4_t){a0, a1, b0, b1};
    }

    // cached stores: full 128B row -> clean line write-back, no RMW
    f4_t* dst = reinterpret_cast<f4_t*>(out + (size_t)orig * 32);
    #pragma unroll
    for (int k = 0; k < 8; ++k) dst[k] = r[k];
}

// ---------- overflow cleanup (empty in practice; guarantees correctness)
__global__ __launch_bounds__(256) void overflow_kernel(
    const f4_t* __restrict__ ovlist, const uint32_t* __restrict__ ovcnt,
    const uint32_t* __restrict__ tbl16, float* __restrict__ out, ResArr ra)
{
    uint32_t n = min(*ovcnt, (uint32_t)OVCAP);
    for (uint32_t i = threadIdx.x; i < n; i += 256) {
        f4_t t = ovlist[i];
        f4_t r[8];
        enc_all16(t.x, t.y, t.z, tbl16, ra, r);
        f4_t* dst = reinterpret_cast<f4_t*>(out + (size_t)__float_as_uint(t.w) * 32);
        #pragma unroll
        for (int k = 0; k < 8; ++k) dst[k] = r[k];
    }
}

// ================= fallback paths =================
__global__ __launch_bounds__(256) void convert_kernel(
    const f2_t* __restrict__ tables, uint32_t* __restrict__ out, int total)
{
    int i = blockIdx.x * 256 + threadIdx.x;
    if (i >= total) return;
    f2_t v = __builtin_nontemporal_load(&tables[i]);
    __half2 h = __floats2half2_rn(v.x, v.y);
    union { __half2 h2; uint32_t u; } cvt; cvt.h2 = h;
    __builtin_nontemporal_store(cvt.u, &out[i]);
}

__global__ __launch_bounds__(256) void hist_kernel(
    const float* __restrict__ pos, uint32_t* __restrict__ counts, int n)
{
    int i = blockIdx.x * 256 + threadIdx.x;
    if (i >= n) return;
    int kx = min(max((int)((pos[(size_t)i*3+0] + 1.f) * 16.f), 0), NB - 1);
    int ky = min(max((int)((pos[(size_t)i*3+1] + 1.f) * 16.f), 0), NB - 1);
    int kz = min(max((int)((pos[(size_t)i*3+2] + 1.f) * 16.f), 0), NB - 1);
    atomicAdd(&counts[(kx << 10) | (ky << 5) | kz], 1u);
}

__global__ __launch_bounds__(1024) void scan_kernel(
    const uint32_t* __restrict__ counts, uint32_t* __restrict__ offsets)
{
    __shared__ uint32_t lds[1024];
    int tid = threadIdx.x;
    uint32_t running = 0;
    for (int chunk = 0; chunk < NBUCKETS; chunk += 1024) {
        uint32_t v = counts[chunk + tid];
        lds[tid] = v;
        __syncthreads();
        #pragma unroll
        for (int off = 1; off < 1024; off <<= 1) {
            uint32_t t = (tid >= off) ? lds[tid - off] : 0u;
            __syncthreads();
            lds[tid] += t;
            __syncthreads();
        }
        offsets[chunk + tid] = running + lds[tid] - v;
        running += lds[1023];
        __syncthreads();
    }
}

__global__ __launch_bounds__(256) void scatter_kernel(
    const float* __restrict__ pos, uint32_t* __restrict__ offs,
    float4* __restrict__ sorted, int n)
{
    int i = blockIdx.x * 256 + threadIdx.x;
    if (i >= n) return;
    float px = pos[(size_t)i*3+0], py = pos[(size_t)i*3+1], pz = pos[(size_t)i*3+2];
    int kx = min(max((int)((px + 1.f) * 16.f), 0), NB - 1);
    int ky = min(max((int)((py + 1.f) * 16.f), 0), NB - 1);
    int kz = min(max((int)((pz + 1.f) * 16.f), 0), NB - 1);
    uint32_t slot = atomicAdd(&offs[(kx << 10) | (ky << 5) | kz], 1u);
    sorted[slot] = make_float4(px, py, pz, __uint_as_float((uint32_t)i));
}

__global__ __launch_bounds__(256) void hashenc_sorted_kernel(
    const float4* __restrict__ sorted, const uint32_t* __restrict__ tbl16,
    float* __restrict__ out, int n_points, int nchunk, ResArr ra)
{
    int bid = blockIdx.x;
    int sbid = (bid & 7) * nchunk + (bid >> 3);
    int gid = sbid * 256 + threadIdx.x;
    if (gid >= n_points) return;
    f4_t t = __builtin_nontemporal_load(reinterpret_cast<const f4_t*>(sorted) + gid);
    f4_t r[8];
    enc_all16(t.x, t.y, t.z, tbl16, ra, r);
    f4_t* dst = reinterpret_cast<f4_t*>(out + (size_t)__float_as_uint(t.w) * 32);
    #pragma unroll
    for (int k = 0; k < 8; ++k) dst[k] = r[k];
}

__global__ __launch_bounds__(256) void hashenc_fp32_kernel(
    const float* __restrict__ pos, const float* __restrict__ tables,
    float* __restrict__ out, int n_points, ResArr res_arr)
{
    int tid = blockIdx.x * 256 + threadIdx.x;
    if (tid >= n_points * NUM_LEVELS) return;
    int level = tid & (NUM_LEVELS - 1);
    int point = tid >> 4;
    float px = pos[(size_t)point*3+0], py = pos[(size_t)point*3+1], pz = pos[(size_t)point*3+2];
    float res = res_arr.r[level];
    int xi[2], yi[2], zi[2]; float wx[2], wy[2], wz[2];
    corner_setup(px, py, pz, res, xi, yi, zi, wx, wy, wz);
    uint32_t hy0 = (uint32_t)yi[0] * 2654435761u, hy1 = (uint32_t)yi[1] * 2654435761u;
    uint32_t hz0 = (uint32_t)zi[0] * 805459861u,  hz1 = (uint32_t)zi[1] * 805459861u;
    const float2* tbl = reinterpret_cast<const float2*>(tables) + (size_t)level * HASH_SIZE;
    float acc0 = 0.f, acc1 = 0.f;
    #pragma unroll
    for (int c = 0; c < 8; ++c) {
        uint32_t hx = (uint32_t)xi[c >> 2];
        uint32_t hy = (c & 2) ? hy1 : hy0;
        uint32_t hz = (c & 1) ? hz1 : hz0;
        float2 f = tbl[(hx ^ hy ^ hz) & HMASK];
        float w = (wx[c >> 2] * wy[(c >> 1) & 1]) * wz[c & 1];
        acc0 += w * f.x; acc1 += w * f.y;
    }
    union { float acc[2]; double d; } u;
    u.acc[0] = acc0; u.acc[1] = acc1;
    __builtin_nontemporal_store(u.d, reinterpret_cast<double*>(out) + ((size_t)point * 16 + level));
}

extern "C" void kernel_launch(void* const* d_in, const int* in_sizes, int n_in,
                              void* d_out, int out_size, void* d_ws, size_t ws_size,
                              hipStream_t stream) {
    const float* pos    = (const float*)d_in[0];
    const float* tables = (const float*)d_in[1];
    float* out = (float*)d_out;
    int n_points = in_sizes[0] / 3;

    // Replicate numpy exactly: RESOLUTIONS[i] = int(floor(16 * exp((i*log(32))/15)))
    ResArr ra;
    const double log32 = log(32.0);
    for (int i = 0; i < NUM_LEVELS; ++i)
        ra.r[i] = (float)(int)floor(16.0 * exp(((double)i * log32) / 15.0));

    const size_t tbl_bytes = (size_t)NUM_LEVELS * HASH_SIZE * sizeof(uint32_t);   // 32 MiB
    const size_t pad_bytes = (size_t)NBUCKETS * CAP * sizeof(f4_t);               // 64 MiB
    const size_t cnt_bytes = (size_t)NBUCKETS * sizeof(uint32_t);                 // 128 KiB
    const size_t ov_bytes  = 16 + (size_t)OVCAP * sizeof(f4_t);
    const size_t need_pad  = tbl_bytes + pad_bytes + cnt_bytes + ov_bytes;        // ~96.3 MiB

    const size_t sorted_bytes = (size_t)n_points * sizeof(float4);
    const size_t need_sorted  = tbl_bytes + sorted_bytes + 2 * cnt_bytes;

    int pblocks = (n_points + 255) / 256;
    int ttotal  = NUM_LEVELS * (int)HASH_SIZE;

    if (ws_size >= need_pad && n_points <= (1 << 21) && (n_points & 3) == 0) {
        char* ws = (char*)d_ws;
        uint32_t* tbl16  = (uint32_t*)(ws);
        f4_t*     padded = (f4_t*)(ws + tbl_bytes);
        uint32_t* counts = (uint32_t*)(ws + tbl_bytes + pad_bytes);
        uint32_t* ovcnt  = (uint32_t*)(ws + tbl_bytes + pad_bytes + cnt_bytes);
        f4_t*     ovlist = (f4_t*)(ws + tbl_bytes + pad_bytes + cnt_bytes + 16);

        hipMemsetAsync(counts, 0, cnt_bytes + 16, stream);
        int cthreads = ttotal / 8;                            // 8 entries/thread
        convert_kernel8<<<(cthreads + 255) / 256, 256, 0, stream>>>(
            (const f4_t*)tables, tbl16, cthreads);
        int nquads = n_points / 4;
        scatter4_kernel<<<(nquads + 255) / 256, 256, 0, stream>>>(
            (const f4_t*)pos, padded, counts, ovcnt, ovlist, nquads);

        int nblocks = NBUCKETS * CAP / 256;                   // 16384
        int nchunk  = nblocks / 8;
        hashenc_lds_kernel<<<nblocks, 256, 0, stream>>>(
            padded, counts, tbl16, out, nchunk, ra);
        overflow_kernel<<<1, 256, 0, stream>>>(ovlist, ovcnt, tbl16, out, ra);
    } else if (ws_size >= need_sorted) {
        char* ws = (char*)d_ws;
        uint32_t* tbl16   = (uint32_t*)(ws);
        float4*   sorted  = (float4*)(ws + tbl_bytes);
        uint32_t* offsets = (uint32_t*)(ws + tbl_bytes + sorted_bytes);
        uint32_t* counts  = (uint32_t*)(ws + tbl_bytes + sorted_bytes + cnt_bytes);

        convert_kernel<<<(ttotal + 255) / 256, 256, 0, stream>>>(
            (const f2_t*)tables, tbl16, ttotal);
        hipMemsetAsync(counts, 0, cnt_bytes, stream);
        hist_kernel<<<pblocks, 256, 0, stream>>>(pos, counts, n_points);
        scan_kernel<<<1, 1024, 0, stream>>>(counts, offsets);
        scatter_kernel<<<pblocks, 256, 0, stream>>>(pos, offsets, sorted, n_points);
        int nchunk = (pblocks + 7) / 8;
        hashenc_sorted_kernel<<<nchunk * 8, 256, 0, stream>>>(
            sorted, tbl16, out, n_points, nchunk, ra);
    } else {
        long long total = (long long)n_points * NUM_LEVELS;
        hashenc_fp32_kernel<<<(int)((total + 255) / 256), 256, 0, stream>>>(
            pos, tables, out, n_points, ra);
    }
}

// Round 14
// 629.409 us; speedup vs baseline: 2.2367x; 1.0772x over previous
//
#include <hip/hip_runtime.h>
#include <hip/hip_fp16.h>
#include <stdint.h>
#include <cmath>

// ============================================================================
// Best-known configuration (r8/r10 structure, ~630 us total):
//   prep: memset + convert(fp32->fp16, 8 entries/thread) + scatter4(padded buckets)
//   main: sorted padded slots, all 16 levels/thread, cached gathers, XCD chunk
//         swizzle, full-128B-row cached stores; overflow cleanup kernel.
// Pinned lessons: NT loads defeat L2 (r12, 2.7x slower); fp32 gathers raise
// footprint (r11, +15%); LDS staging is VALU-bound (r13, +11%); L1 bypass
// neutral (r5); occupancy-insensitive (r8/r9). Main kernel sits at the
// fine-level random-gather miss wall (~0.35 lines/cyc/CU).
// ============================================================================

static constexpr int NUM_LEVELS = 16;
static constexpr uint32_t HASH_SIZE = 1u << 19;
static constexpr uint32_t HMASK = HASH_SIZE - 1u;
static constexpr int NB = 32;                     // bucket grid per axis
static constexpr int NBUCKETS = NB * NB * NB;     // 32768
static constexpr int CAP = 128;                   // padded slots/bucket (avg fill ~64)
static constexpr int OVCAP = 8192;                // overflow list capacity

typedef float    f2_t __attribute__((ext_vector_type(2)));
typedef float    f4_t __attribute__((ext_vector_type(4)));
typedef uint32_t u4_t __attribute__((ext_vector_type(4)));

struct ResArr { float r[NUM_LEVELS]; };

// ---------- corner indices + trilinear weights for one level (order = _OFFSETS)
__device__ __forceinline__ void make_corners(
    float px, float py, float pz, float res, uint32_t* idx, float* w)
{
    float sx = ((px + 1.0f) * 0.5f) * res;
    float sy = ((py + 1.0f) * 0.5f) * res;
    float sz = ((pz + 1.0f) * 0.5f) * res;

    float fx = floorf(sx), fy = floorf(sy), fz = floorf(sz);
    float rx = sx - fx, ry = sy - fy, rz = sz - fz;

    float x0f = fminf(fmaxf(fx, 0.f), res), x1f = fminf(fmaxf(fx + 1.f, 0.f), res);
    float y0f = fminf(fmaxf(fy, 0.f), res), y1f = fminf(fmaxf(fy + 1.f, 0.f), res);
    float z0f = fminf(fmaxf(fz, 0.f), res), z1f = fminf(fmaxf(fz + 1.f, 0.f), res);

    uint32_t x0 = (uint32_t)x0f, x1 = (uint32_t)x1f;
    uint32_t hy0 = (uint32_t)y0f * 2654435761u, hy1 = (uint32_t)y1f * 2654435761u;
    uint32_t hz0 = (uint32_t)z0f * 805459861u,  hz1 = (uint32_t)z1f * 805459861u;

    float wx0 = 1.f - rx, wx1 = rx;
    float wy0 = 1.f - ry, wy1 = ry;
    float wz0 = 1.f - rz, wz1 = rz;

    idx[0] = (x0 ^ hy0 ^ hz0) & HMASK; w[0] = (wx0 * wy0) * wz0;
    idx[1] = (x0 ^ hy0 ^ hz1) & HMASK; w[1] = (wx0 * wy0) * wz1;
    idx[2] = (x0 ^ hy1 ^ hz0) & HMASK; w[2] = (wx0 * wy1) * wz0;
    idx[3] = (x0 ^ hy1 ^ hz1) & HMASK; w[3] = (wx0 * wy1) * wz1;
    idx[4] = (x1 ^ hy0 ^ hz0) & HMASK; w[4] = (wx1 * wy0) * wz0;
    idx[5] = (x1 ^ hy0 ^ hz1) & HMASK; w[5] = (wx1 * wy0) * wz1;
    idx[6] = (x1 ^ hy1 ^ hz0) & HMASK; w[6] = (wx1 * wy1) * wz0;
    idx[7] = (x1 ^ hy1 ^ hz1) & HMASK; w[7] = (wx1 * wy1) * wz1;
}

// ---------- all 16 levels for one point from packed fp16 tables (cached loads)
__device__ __forceinline__ void enc_all16(
    float px, float py, float pz, const uint32_t* __restrict__ tbl16,
    const ResArr& ra, f4_t r[8])
{
    #pragma unroll
    for (int p = 0; p < 8; ++p) {
        const uint32_t* tA = tbl16 + (size_t)(2 * p)     * HASH_SIZE;
        const uint32_t* tB = tbl16 + (size_t)(2 * p + 1) * HASH_SIZE;
        uint32_t idxA[8], idxB[8];
        float wA[8], wB[8];
        make_corners(px, py, pz, ra.r[2 * p],     idxA, wA);
        make_corners(px, py, pz, ra.r[2 * p + 1], idxB, wB);

        uint32_t g[16];
        #pragma unroll
        for (int i = 0; i < 8; ++i) g[i]     = tA[idxA[i]];
        #pragma unroll
        for (int i = 0; i < 8; ++i) g[8 + i] = tB[idxB[i]];

        float a0 = 0.f, a1 = 0.f, b0 = 0.f, b1 = 0.f;
        #pragma unroll
        for (int i = 0; i < 8; ++i) {
            union { uint32_t u; __half2 h2; } c; c.u = g[i];
            float2 f = __half22float2(c.h2);
            a0 += wA[i] * f.x; a1 += wA[i] * f.y;
        }
        #pragma unroll
        for (int i = 0; i < 8; ++i) {
            union { uint32_t u; __half2 h2; } c; c.u = g[8 + i];
            float2 f = __half22float2(c.h2);
            b0 += wB[i] * f.x; b1 += wB[i] * f.y;
        }
        r[p] = (f4_t){a0, a1, b0, b1};
    }
}

// ---------- conv: 8 table entries (64B in / 32B out) per thread
__global__ __launch_bounds__(256) void convert_kernel8(
    const f4_t* __restrict__ tables4, uint32_t* __restrict__ tbl16, int nthreads)
{
    int t = blockIdx.x * 256 + threadIdx.x;
    if (t >= nthreads) return;
    const f4_t* src = tables4 + (size_t)t * 4;
    f4_t v0 = __builtin_nontemporal_load(src + 0);
    f4_t v1 = __builtin_nontemporal_load(src + 1);
    f4_t v2 = __builtin_nontemporal_load(src + 2);
    f4_t v3 = __builtin_nontemporal_load(src + 3);
    union { __half2 h2; uint32_t u; } c0, c1, c2, c3, c4, c5, c6, c7;
    c0.h2 = __floats2half2_rn(v0.x, v0.y); c1.h2 = __floats2half2_rn(v0.z, v0.w);
    c2.h2 = __floats2half2_rn(v1.x, v1.y); c3.h2 = __floats2half2_rn(v1.z, v1.w);
    c4.h2 = __floats2half2_rn(v2.x, v2.y); c5.h2 = __floats2half2_rn(v2.z, v2.w);
    c6.h2 = __floats2half2_rn(v3.x, v3.y); c7.h2 = __floats2half2_rn(v3.z, v3.w);
    u4_t o0 = {c0.u, c1.u, c2.u, c3.u};
    u4_t o1 = {c4.u, c5.u, c6.u, c7.u};
    u4_t* dst = reinterpret_cast<u4_t*>(tbl16) + (size_t)t * 2;
    __builtin_nontemporal_store(o0, dst + 0);
    __builtin_nontemporal_store(o1, dst + 1);
}

// ---------- scatter: 4 points per thread via 3 coalesced f4 loads
__global__ __launch_bounds__(256) void scatter4_kernel(
    const f4_t* __restrict__ pos4, f4_t* __restrict__ padded,
    uint32_t* __restrict__ counts, uint32_t* __restrict__ ovcnt,
    f4_t* __restrict__ ovlist, int nquads)
{
    int q = blockIdx.x * 256 + threadIdx.x;
    if (q >= nquads) return;
    f4_t a = __builtin_nontemporal_load(pos4 + (size_t)q * 3 + 0);
    f4_t b = __builtin_nontemporal_load(pos4 + (size_t)q * 3 + 1);
    f4_t c = __builtin_nontemporal_load(pos4 + (size_t)q * 3 + 2);
    float xs[4] = {a.x, a.w, b.z, c.y};
    float ys[4] = {a.y, b.x, b.w, c.z};
    float zs[4] = {a.z, b.y, c.x, c.w};
    #pragma unroll
    for (int j = 0; j < 4; ++j) {
        int kx = min(max((int)((xs[j] + 1.f) * 16.f), 0), NB - 1);
        int ky = min(max((int)((ys[j] + 1.f) * 16.f), 0), NB - 1);
        int kz = min(max((int)((zs[j] + 1.f) * 16.f), 0), NB - 1);
        int bucket = (kx << 10) | (ky << 5) | kz;
        uint32_t rank = atomicAdd(&counts[bucket], 1u);
        f4_t rec = {xs[j], ys[j], zs[j], __uint_as_float((uint32_t)(q * 4 + j))};
        if (rank < (uint32_t)CAP) {
            padded[(size_t)bucket * CAP + rank] = rec;
        } else {
            uint32_t ov = atomicAdd(ovcnt, 1u);   // ~never (Poisson(64) > 128)
            if (ov < (uint32_t)OVCAP) ovlist[ov] = rec;
        }
    }
}

// ---------- main: one thread = one padded slot (gid == bucket*CAP + slot).
// Chunked XCD swizzle keeps each spatial region on one XCD's L2.
__global__ __launch_bounds__(256) void hashenc_padded_kernel(
    const f4_t* __restrict__ padded, const uint32_t* __restrict__ counts,
    const uint32_t* __restrict__ tbl16, float* __restrict__ out,
    int nchunk, ResArr ra)
{
    int bid = blockIdx.x;
    int sbid = (bid & 7) * nchunk + (bid >> 3);
    int gid = sbid * 256 + threadIdx.x;
    int bucket = gid >> 7;                 // CAP == 128
    int slot   = gid & (CAP - 1);
    uint32_t cnt = counts[bucket];
    if (slot >= (int)min(cnt, (uint32_t)CAP)) return;

    f4_t t = padded[gid];
    float px = t.x, py = t.y, pz = t.z;
    uint32_t orig = __float_as_uint(t.w);

    f4_t r[8];
    enc_all16(px, py, pz, tbl16, ra, r);

    // cached stores: full 128B row -> clean line write-back, no RMW
    f4_t* dst = reinterpret_cast<f4_t*>(out + (size_t)orig * 32);
    #pragma unroll
    for (int k = 0; k < 8; ++k) dst[k] = r[k];
}

// ---------- overflow cleanup (empty in practice; guarantees correctness)
__global__ __launch_bounds__(256) void overflow_kernel(
    const f4_t* __restrict__ ovlist, const uint32_t* __restrict__ ovcnt,
    const uint32_t* __restrict__ tbl16, float* __restrict__ out, ResArr ra)
{
    uint32_t n = min(*ovcnt, (uint32_t)OVCAP);
    for (uint32_t i = threadIdx.x; i < n; i += 256) {
        f4_t t = ovlist[i];
        f4_t r[8];
        enc_all16(t.x, t.y, t.z, tbl16, ra, r);
        f4_t* dst = reinterpret_cast<f4_t*>(out + (size_t)__float_as_uint(t.w) * 32);
        #pragma unroll
        for (int k = 0; k < 8; ++k) dst[k] = r[k];
    }
}

// ================= fallback paths =================
__global__ __launch_bounds__(256) void convert_kernel(
    const f2_t* __restrict__ tables, uint32_t* __restrict__ out, int total)
{
    int i = blockIdx.x * 256 + threadIdx.x;
    if (i >= total) return;
    f2_t v = __builtin_nontemporal_load(&tables[i]);
    __half2 h = __floats2half2_rn(v.x, v.y);
    union { __half2 h2; uint32_t u; } cvt; cvt.h2 = h;
    __builtin_nontemporal_store(cvt.u, &out[i]);
}

__global__ __launch_bounds__(256) void hist_kernel(
    const float* __restrict__ pos, uint32_t* __restrict__ counts, int n)
{
    int i = blockIdx.x * 256 + threadIdx.x;
    if (i >= n) return;
    int kx = min(max((int)((pos[(size_t)i*3+0] + 1.f) * 16.f), 0), NB - 1);
    int ky = min(max((int)((pos[(size_t)i*3+1] + 1.f) * 16.f), 0), NB - 1);
    int kz = min(max((int)((pos[(size_t)i*3+2] + 1.f) * 16.f), 0), NB - 1);
    atomicAdd(&counts[(kx << 10) | (ky << 5) | kz], 1u);
}

__global__ __launch_bounds__(1024) void scan_kernel(
    const uint32_t* __restrict__ counts, uint32_t* __restrict__ offsets)
{
    __shared__ uint32_t lds[1024];
    int tid = threadIdx.x;
    uint32_t running = 0;
    for (int chunk = 0; chunk < NBUCKETS; chunk += 1024) {
        uint32_t v = counts[chunk + tid];
        lds[tid] = v;
        __syncthreads();
        #pragma unroll
        for (int off = 1; off < 1024; off <<= 1) {
            uint32_t t = (tid >= off) ? lds[tid - off] : 0u;
            __syncthreads();
            lds[tid] += t;
            __syncthreads();
        }
        offsets[chunk + tid] = running + lds[tid] - v;
        running += lds[1023];
        __syncthreads();
    }
}

__global__ __launch_bounds__(256) void scatter_kernel(
    const float* __restrict__ pos, uint32_t* __restrict__ offs,
    float4* __restrict__ sorted, int n)
{
    int i = blockIdx.x * 256 + threadIdx.x;
    if (i >= n) return;
    float px = pos[(size_t)i*3+0], py = pos[(size_t)i*3+1], pz = pos[(size_t)i*3+2];
    int kx = min(max((int)((px + 1.f) * 16.f), 0), NB - 1);
    int ky = min(max((int)((py + 1.f) * 16.f), 0), NB - 1);
    int kz = min(max((int)((pz + 1.f) * 16.f), 0), NB - 1);
    uint32_t slot = atomicAdd(&offs[(kx << 10) | (ky << 5) | kz], 1u);
    sorted[slot] = make_float4(px, py, pz, __uint_as_float((uint32_t)i));
}

__global__ __launch_bounds__(256) void hashenc_sorted_kernel(
    const float4* __restrict__ sorted, const uint32_t* __restrict__ tbl16,
    float* __restrict__ out, int n_points, int nchunk, ResArr ra)
{
    int bid = blockIdx.x;
    int sbid = (bid & 7) * nchunk + (bid >> 3);
    int gid = sbid * 256 + threadIdx.x;
    if (gid >= n_points) return;
    f4_t t = __builtin_nontemporal_load(reinterpret_cast<const f4_t*>(sorted) + gid);
    f4_t r[8];
    enc_all16(t.x, t.y, t.z, tbl16, ra, r);
    f4_t* dst = reinterpret_cast<f4_t*>(out + (size_t)__float_as_uint(t.w) * 32);
    #pragma unroll
    for (int k = 0; k < 8; ++k) dst[k] = r[k];
}

__global__ __launch_bounds__(256) void hashenc_fp32_kernel(
    const float* __restrict__ pos, const float* __restrict__ tables,
    float* __restrict__ out, int n_points, ResArr res_arr)
{
    int tid = blockIdx.x * 256 + threadIdx.x;
    if (tid >= n_points * NUM_LEVELS) return;
    int level = tid & (NUM_LEVELS - 1);
    int point = tid >> 4;
    float px = pos[(size_t)point*3+0], py = pos[(size_t)point*3+1], pz = pos[(size_t)point*3+2];
    uint32_t idx[8]; float w[8];
    make_corners(px, py, pz, res_arr.r[level], idx, w);
    const float2* tbl = reinterpret_cast<const float2*>(tables) + (size_t)level * HASH_SIZE;
    float acc0 = 0.f, acc1 = 0.f;
    #pragma unroll
    for (int i = 0; i < 8; ++i) {
        float2 f = tbl[idx[i]];
        acc0 += w[i] * f.x; acc1 += w[i] * f.y;
    }
    union { float acc[2]; double d; } u;
    u.acc[0] = acc0; u.acc[1] = acc1;
    __builtin_nontemporal_store(u.d, reinterpret_cast<double*>(out) + ((size_t)point * 16 + level));
}

extern "C" void kernel_launch(void* const* d_in, const int* in_sizes, int n_in,
                              void* d_out, int out_size, void* d_ws, size_t ws_size,
                              hipStream_t stream) {
    const float* pos    = (const float*)d_in[0];
    const float* tables = (const float*)d_in[1];
    float* out = (float*)d_out;
    int n_points = in_sizes[0] / 3;

    // Replicate numpy exactly: RESOLUTIONS[i] = int(floor(16 * exp((i*log(32))/15)))
    ResArr ra;
    const double log32 = log(32.0);
    for (int i = 0; i < NUM_LEVELS; ++i)
        ra.r[i] = (float)(int)floor(16.0 * exp(((double)i * log32) / 15.0));

    const size_t tbl_bytes = (size_t)NUM_LEVELS * HASH_SIZE * sizeof(uint32_t);   // 32 MiB
    const size_t pad_bytes = (size_t)NBUCKETS * CAP * sizeof(f4_t);               // 64 MiB
    const size_t cnt_bytes = (size_t)NBUCKETS * sizeof(uint32_t);                 // 128 KiB
    const size_t ov_bytes  = 16 + (size_t)OVCAP * sizeof(f4_t);
    const size_t need_pad  = tbl_bytes + pad_bytes + cnt_bytes + ov_bytes;        // ~96.3 MiB

    const size_t sorted_bytes = (size_t)n_points * sizeof(float4);
    const size_t need_sorted  = tbl_bytes + sorted_bytes + 2 * cnt_bytes;

    int pblocks = (n_points + 255) / 256;
    int ttotal  = NUM_LEVELS * (int)HASH_SIZE;

    if (ws_size >= need_pad && n_points <= (1 << 21) && (n_points & 3) == 0) {
        char* ws = (char*)d_ws;
        uint32_t* tbl16  = (uint32_t*)(ws);
        f4_t*     padded = (f4_t*)(ws + tbl_bytes);
        uint32_t* counts = (uint32_t*)(ws + tbl_bytes + pad_bytes);
        uint32_t* ovcnt  = (uint32_t*)(ws + tbl_bytes + pad_bytes + cnt_bytes);
        f4_t*     ovlist = (f4_t*)(ws + tbl_bytes + pad_bytes + cnt_bytes + 16);

        hipMemsetAsync(counts, 0, cnt_bytes + 16, stream);
        int cthreads = ttotal / 8;                            // 8 entries/thread
        convert_kernel8<<<(cthreads + 255) / 256, 256, 0, stream>>>(
            (const f4_t*)tables, tbl16, cthreads);
        int nquads = n_points / 4;
        scatter4_kernel<<<(nquads + 255) / 256, 256, 0, stream>>>(
            (const f4_t*)pos, padded, counts, ovcnt, ovlist, nquads);

        int nblocks = NBUCKETS * CAP / 256;                   // 16384
        int nchunk  = nblocks / 8;
        hashenc_padded_kernel<<<nblocks, 256, 0, stream>>>(
            padded, counts, tbl16, out, nchunk, ra);
        overflow_kernel<<<1, 256, 0, stream>>>(ovlist, ovcnt, tbl16, out, ra);
    } else if (ws_size >= need_sorted) {
        char* ws = (char*)d_ws;
        uint32_t* tbl16   = (uint32_t*)(ws);
        float4*   sorted  = (float4*)(ws + tbl_bytes);
        uint32_t* offsets = (uint32_t*)(ws + tbl_bytes + sorted_bytes);
        uint32_t* counts  = (uint32_t*)(ws + tbl_bytes + sorted_bytes + cnt_bytes);

        convert_kernel<<<(ttotal + 255) / 256, 256, 0, stream>>>(
            (const f2_t*)tables, tbl16, ttotal);
        hipMemsetAsync(counts, 0, cnt_bytes, stream);
        hist_kernel<<<pblocks, 256, 0, stream>>>(pos, counts, n_points);
        scan_kernel<<<1, 1024, 0, stream>>>(counts, offsets);
        scatter_kernel<<<pblocks, 256, 0, stream>>>(pos, offsets, sorted, n_points);
        int nchunk = (pblocks + 7) / 8;
        hashenc_sorted_kernel<<<nchunk * 8, 256, 0, stream>>>(
            sorted, tbl16, out, n_points, nchunk, ra);
    } else {
        long long total = (long long)n_points * NUM_LEVELS;
        hashenc_fp32_kernel<<<(int)((total + 255) / 256), 256, 0, stream>>>(
            pos, tables, out, n_points, ra);
    }
}